// Round 1
// baseline (184.251 us; speedup 1.0000x reference)
//
#include <hip/hip_runtime.h>

#define NS 32768
#define NC 395
#define FD 512
#define NEL (NC * FD)

#define HBLK 64   // histogram blocks
#define QPC 4     // gather splits per class

// Static device scratch — every slot rewritten each call.
__device__ int   g_histp[HBLK * NC];      // per-block histograms (no pre-zero needed)
__device__ int   g_off[NC + 1];           // class segment offsets (exclusive prefix)
__device__ int   g_cur[NC];               // scatter cursors
__device__ int   g_sorted[NS];            // row indices sorted by class
__device__ float g_part[QPC * 2 * NC * FD]; // 6.5 MB partial sums

// ---------------------------------------------------------------------------
// K0a: per-block LDS histogram of targets, written to private slabs (no global
// atomics, no zeroing kernel needed — every slot overwritten).
__global__ __launch_bounds__(256)
void k_hist(const int* __restrict__ targets) {
    __shared__ int h[NC];
    int t = threadIdx.x;
    for (int c = t; c < NC; c += 256) h[c] = 0;
    __syncthreads();
    int base = blockIdx.x * 512;
    atomicAdd(&h[targets[base + t]], 1);
    atomicAdd(&h[targets[base + t + 256]], 1);
    __syncthreads();
    for (int c = t; c < NC; c += 256) g_histp[blockIdx.x * NC + c] = h[c];
}

// K0b: single block — reduce the 64 histograms, exclusive prefix sum,
// init scatter cursors, zero the output scalar.
__global__ __launch_bounds__(512)
void k_prefix(float* __restrict__ out) {
    __shared__ int sh[512];
    int t = threadIdx.x;
    int v = 0;
    if (t < NC)
        for (int b = 0; b < HBLK; b++) v += g_histp[b * NC + t];
    sh[t] = v;
    __syncthreads();
    for (int off = 1; off < 512; off <<= 1) {
        int x = sh[t];
        if (t >= off) x += sh[t - off];
        __syncthreads();
        sh[t] = x;
        __syncthreads();
    }
    if (t < NC) {
        int excl = sh[t] - v;
        g_off[t] = excl;
        g_cur[t] = excl;
    }
    if (t == NC - 1) g_off[NC] = sh[t];
    if (t == 0) out[0] = 0.0f;
}

// K0c: scatter row indices into class-sorted order (order within a class is
// irrelevant for the sum).
__global__ __launch_bounds__(256)
void k_scatter(const int* __restrict__ targets) {
    int i = blockIdx.x * 256 + threadIdx.x;
    int c = targets[i];
    int pos = atomicAdd(&g_cur[c], 1);
    g_sorted[pos] = i;
}

// ---------------------------------------------------------------------------
__device__ __forceinline__ void f4add(float4& a, const float4 b) {
    a.x += b.x; a.y += b.y; a.z += b.z; a.w += b.w;
}

// K1: one block per (class, quarter). No scan phase, no index LDS — indices
// come straight from the L2-hot sorted list. 4 waves = 2 per modality; within
// a modality the two waves take even/odd list slots and each LANE covers a
// full 2KB row (two float4 at lane, lane+64). 8 row-loads in flight per wave,
// and with ~21 rows/wave the pipeline actually stays full (vs ~5 rows before).
__global__ __launch_bounds__(256)
void k_gather(const float4* __restrict__ m1, const float4* __restrict__ m2) {
    int c   = blockIdx.x >> 2;
    int q   = blockIdx.x & (QPC - 1);
    int tid = threadIdx.x;

    int o0 = g_off[c], o1 = g_off[c + 1];
    int n  = o1 - o0;
    int s0 = o0 + ((n * q) >> 2);
    int s1 = o0 + ((n * (q + 1)) >> 2);

    int wid  = tid >> 6;
    int mod  = wid >> 1;      // modality (wave-uniform)
    int par  = wid & 1;       // even/odd list-slot subset (wave-uniform)
    int lane = tid & 63;
    const float4* src = mod ? m2 : m1;

    float4 z = make_float4(0.f, 0.f, 0.f, 0.f);
    float4 aA0 = z, aB0 = z, aA1 = z, aB1 = z;

    __shared__ float4 cmb[2][128];   // wave-pair combine buffer (4 KB total LDS)

    int j = s0 + par;
    // 4 rows per iteration (stride 2 within this wave), 8 loads in flight.
    for (; j + 6 < s1; j += 8) {
        int i0 = g_sorted[j];
        int i1 = g_sorted[j + 2];
        int i2 = g_sorted[j + 4];
        int i3 = g_sorted[j + 6];
        const float4* p0 = src + (size_t)i0 * 128;
        const float4* p1 = src + (size_t)i1 * 128;
        const float4* p2 = src + (size_t)i2 * 128;
        const float4* p3 = src + (size_t)i3 * 128;
        float4 vA0 = p0[lane], vB0 = p0[lane + 64];
        float4 vA1 = p1[lane], vB1 = p1[lane + 64];
        float4 vA2 = p2[lane], vB2 = p2[lane + 64];
        float4 vA3 = p3[lane], vB3 = p3[lane + 64];
        f4add(aA0, vA0); f4add(aB0, vB0);
        f4add(aA1, vA1); f4add(aB1, vB1);
        f4add(aA0, vA2); f4add(aB0, vB2);
        f4add(aA1, vA3); f4add(aB1, vB3);
    }
    for (; j < s1; j += 2) {
        const float4* p = src + (size_t)g_sorted[j] * 128;
        f4add(aA0, p[lane]); f4add(aB0, p[lane + 64]);
    }
    f4add(aA0, aA1); f4add(aB0, aB1);

    // combine the wave pair, store partial slab
    if (par == 0) {
        cmb[mod][lane]      = aA0;
        cmb[mod][lane + 64] = aB0;
    }
    __syncthreads();
    if (par == 1) {
        float4 rA = cmb[mod][lane];      f4add(rA, aA0);
        float4 rB = cmb[mod][lane + 64]; f4add(rB, aB0);
        float4* dst = reinterpret_cast<float4*>(g_part);
        size_t base = (((size_t)q * 2 + mod) * NC + c) * 128;
        dst[base + lane]      = rA;
        dst[base + lane + 64] = rB;
    }
}

// ---------------------------------------------------------------------------
__device__ __forceinline__ float smooth_l1(float d) {
    d = fabsf(d);
    return d < 1.0f ? 0.5f * d * d : d - 0.5f;
}

// K2: combine QPC partials per modality, SmoothL1 weighted by count,
// two-level reduce. Counts come straight from g_off.
__global__ void k_loss(const float* __restrict__ centers,
                       float* __restrict__ out) {
    __shared__ float scnt[NC];
    int t = threadIdx.x;   // 256
    for (int c = t; c < NC; c += 256)
        scnt[c] = (float)(g_off[c + 1] - g_off[c]);
    __syncthreads();

    float val = 0.0f;
    for (int gid = blockIdx.x * 256 + t; gid < NEL; gid += gridDim.x * 256) {
        int c = gid >> 9;          // FD == 512
        float cnt = scnt[c];
        if (cnt > 0.0f) {
            float s1 = 0.0f, s2 = 0.0f;
            #pragma unroll
            for (int k = 0; k < QPC; k++) {
                s1 += g_part[(size_t)(2 * k)     * NEL + gid];
                s2 += g_part[(size_t)(2 * k + 1) * NEL + gid];
            }
            float ctr = centers[gid];
            float inv = 1.0f / cnt;
            val += cnt * (smooth_l1(s1 * inv - ctr) + smooth_l1(s2 * inv - ctr));
        }
    }

    for (int off = 32; off > 0; off >>= 1)
        val += __shfl_down(val, off, 64);
    __shared__ float wsum[4];
    int lane = t & 63, wid = t >> 6;
    if (lane == 0) wsum[wid] = val;
    __syncthreads();
    if (t == 0) {
        float sm = wsum[0] + wsum[1] + wsum[2] + wsum[3];
        atomicAdd(out, sm * 5.9604644775390625e-08f);  // 1/(N*D) = 2^-24
    }
}

extern "C" void kernel_launch(void* const* d_in, const int* in_sizes, int n_in,
                              void* d_out, int out_size, void* d_ws, size_t ws_size,
                              hipStream_t stream) {
    const float4* m1 = (const float4*)d_in[0];
    const float4* m2 = (const float4*)d_in[1];
    const float* centers = (const float*)d_in[2];
    const int* targets = (const int*)d_in[3];
    float* out = (float*)d_out;

    k_hist<<<NS / 512, 256, 0, stream>>>(targets);
    k_prefix<<<1, 512, 0, stream>>>(out);
    k_scatter<<<NS / 256, 256, 0, stream>>>(targets);
    k_gather<<<NC * QPC, 256, 0, stream>>>(m1, m2);
    k_loss<<<512, 256, 0, stream>>>(centers, out);
}